// Round 7
// baseline (1222.937 us; speedup 1.0000x reference)
//
#include <hip/hip_runtime.h>

#define N_SITES  100000
#define N_BONDS  800000
#define N_GRAPHS 1000

// ---------- MFMA types ----------
typedef short bfx8 __attribute__((ext_vector_type(8)));
typedef float fx4  __attribute__((ext_vector_type(4)));

__device__ __forceinline__ short b16(float x){ __bf16 h = (__bf16)x; return *(short*)&h; }

// ---------- swizzled bf16 LDS helpers (round-6 validated) ----------
__device__ __forceinline__ bfx8 ldfrag128(const short* buf, int row, int k){
  int off = (row*128 + k*2) ^ ((row&7)<<4);
  return *(const bfx8*)((const char*)buf + off);
}
__device__ __forceinline__ bfx8 ldfrag64(const short* buf, int row, int k){
  int off = (row*64 + k*2) ^ ((row&7)<<4);
  return *(const bfx8*)((const char*)buf + off);
}
__device__ __forceinline__ void stb16_128(short* buf, int row, int col, float v){
  int off = (row*128 + col*2) ^ ((row&7)<<4);
  *(__bf16*)((char*)buf + off) = (__bf16)v;
}
__device__ __forceinline__ void stb16_64(short* buf, int row, int col, float v){
  int off = (row*64 + col*2) ^ ((row&7)<<4);
  *(__bf16*)((char*)buf + off) = (__bf16)v;
}

// ---------- direct-global A-fragments (f32 rows -> bf16 frag) ----------
__device__ __forceinline__ bfx8 fragG(const float* rp, int k){
  float4 u = *(const float4*)(rp + k);
  float4 v = *(const float4*)(rp + k + 4);
  bfx8 r;
  r[0]=b16(u.x); r[1]=b16(u.y); r[2]=b16(u.z); r[3]=b16(u.w);
  r[4]=b16(v.x); r[5]=b16(v.y); r[6]=b16(v.z); r[7]=b16(v.w);
  return r;
}
__device__ __forceinline__ bfx8 fragGs(const float* rp, float s, int k){
  float4 u = *(const float4*)(rp + k);
  float4 v = *(const float4*)(rp + k + 4);
  bfx8 r;
  r[0]=b16(u.x*s); r[1]=b16(u.y*s); r[2]=b16(u.z*s); r[3]=b16(u.w*s);
  r[4]=b16(v.x*s); r[5]=b16(v.y*s); r[6]=b16(v.z*s); r[7]=b16(v.w*s);
  return r;
}

// ---------- 64x64 GEMM pieces ----------
// A-frag row = mt*16 + (lane%16), k = kt*32 + (lane/16)*8; B stored [n][k] swz;
// C/D: row = mt*16 + (lane/16)*4 + i, col = nt*16 + (lane%16). (validated r6)
__device__ __forceinline__ void gemm64(const short* Ab, const short* Bw,
                                       fx4 (&acc)[4][4], int q, int c){
  #pragma unroll
  for (int kt = 0; kt < 2; ++kt){
    int k = kt*32 + q*8;
    bfx8 a0 = ldfrag128(Ab,  0+c, k);
    bfx8 a1 = ldfrag128(Ab, 16+c, k);
    bfx8 a2 = ldfrag128(Ab, 32+c, k);
    bfx8 a3 = ldfrag128(Ab, 48+c, k);
    #pragma unroll
    for (int nt = 0; nt < 4; ++nt){
      bfx8 b = ldfrag128(Bw, nt*16+c, k);
      acc[0][nt] = __builtin_amdgcn_mfma_f32_16x16x32_bf16(a0, b, acc[0][nt], 0,0,0);
      acc[1][nt] = __builtin_amdgcn_mfma_f32_16x16x32_bf16(a1, b, acc[1][nt], 0,0,0);
      acc[2][nt] = __builtin_amdgcn_mfma_f32_16x16x32_bf16(a2, b, acc[2][nt], 0,0,0);
      acc[3][nt] = __builtin_amdgcn_mfma_f32_16x16x32_bf16(a3, b, acc[3][nt], 0,0,0);
    }
  }
}
__device__ __forceinline__ void gemmG(const float* const (&rp)[4], const short* Bw,
                                      fx4 (&acc)[4][4], int q, int c){
  #pragma unroll
  for (int kt = 0; kt < 2; ++kt){
    int k = kt*32 + q*8;
    bfx8 a0 = fragG(rp[0], k);
    bfx8 a1 = fragG(rp[1], k);
    bfx8 a2 = fragG(rp[2], k);
    bfx8 a3 = fragG(rp[3], k);
    #pragma unroll
    for (int nt = 0; nt < 4; ++nt){
      bfx8 b = ldfrag128(Bw, nt*16+c, k);
      acc[0][nt] = __builtin_amdgcn_mfma_f32_16x16x32_bf16(a0, b, acc[0][nt], 0,0,0);
      acc[1][nt] = __builtin_amdgcn_mfma_f32_16x16x32_bf16(a1, b, acc[1][nt], 0,0,0);
      acc[2][nt] = __builtin_amdgcn_mfma_f32_16x16x32_bf16(a2, b, acc[2][nt], 0,0,0);
      acc[3][nt] = __builtin_amdgcn_mfma_f32_16x16x32_bf16(a3, b, acc[3][nt], 0,0,0);
    }
  }
}
__device__ __forceinline__ void gemmGs(const float* const (&rp)[4], const float (&sc)[4],
                                       const short* Bw, fx4 (&acc)[4][4], int q, int c){
  #pragma unroll
  for (int kt = 0; kt < 2; ++kt){
    int k = kt*32 + q*8;
    bfx8 a0 = fragGs(rp[0], sc[0], k);
    bfx8 a1 = fragGs(rp[1], sc[1], k);
    bfx8 a2 = fragGs(rp[2], sc[2], k);
    bfx8 a3 = fragGs(rp[3], sc[3], k);
    #pragma unroll
    for (int nt = 0; nt < 4; ++nt){
      bfx8 b = ldfrag128(Bw, nt*16+c, k);
      acc[0][nt] = __builtin_amdgcn_mfma_f32_16x16x32_bf16(a0, b, acc[0][nt], 0,0,0);
      acc[1][nt] = __builtin_amdgcn_mfma_f32_16x16x32_bf16(a1, b, acc[1][nt], 0,0,0);
      acc[2][nt] = __builtin_amdgcn_mfma_f32_16x16x32_bf16(a2, b, acc[2][nt], 0,0,0);
      acc[3][nt] = __builtin_amdgcn_mfma_f32_16x16x32_bf16(a3, b, acc[3][nt], 0,0,0);
    }
  }
}
__device__ __forceinline__ void initbiasG(fx4 (&acc)[4][4], const float* B, int c){
  #pragma unroll
  for (int nt = 0; nt < 4; ++nt){
    float bv = B[nt*16+c];
    fx4 v = {bv, bv, bv, bv};
    #pragma unroll
    for (int mt = 0; mt < 4; ++mt) acc[mt][nt] = v;
  }
}
__device__ __forceinline__ void wbC128(short* dst, fx4 (&acc)[4][4], int q, int c){
  #pragma unroll
  for (int mt = 0; mt < 4; ++mt)
    #pragma unroll
    for (int nt = 0; nt < 4; ++nt)
      #pragma unroll
      for (int i = 0; i < 4; ++i)
        stb16_128(dst, mt*16+q*4+i, nt*16+c, fmaxf(acc[mt][nt][i], 0.f));
}

// transpose+bf16+swizzle weight staging: src [64k][64n] f32 -> dst [n][k] bf16
__device__ __forceinline__ void stage_wt(short* dst, const float* __restrict__ src,
                                         int tid, int nth){
  for (int i = tid; i < 4096; i += nth){
    int k = i >> 6, n = i & 63;
    int off = (n*128 + k*2) ^ ((n&7)<<4);
    *(__bf16*)((char*)dst + off) = (__bf16)src[i];
  }
}

// preload the 64->32->64 tail weights as register B-frags
__device__ __forceinline__ void preload_tail(const float* __restrict__ w2,
                                             const float* __restrict__ w3,
                                             bfx8 (&u2)[2][2], bfx8 (&u3)[4],
                                             int q, int c){
  #pragma unroll
  for (int kt = 0; kt < 2; ++kt)
    #pragma unroll
    for (int nt = 0; nt < 2; ++nt)
      #pragma unroll
      for (int j = 0; j < 8; ++j)
        u2[kt][nt][j] = b16(w2[(kt*32 + q*8 + j)*32 + nt*16 + c]);
  #pragma unroll
  for (int nt = 0; nt < 4; ++nt)
    #pragma unroll
    for (int j = 0; j < 8; ++j)
      u3[nt][j] = b16(w3[(q*8 + j)*64 + nt*16 + c]);
}

// fc2(64->32) + fc3(32->64) operating on X (holds H1; H2 written in place)
__device__ __forceinline__ void tail3264(short* X, const bfx8 (&u2)[2][2], const bfx8 (&u3)[4],
                                         const float* __restrict__ b2g,
                                         const float* __restrict__ b3g,
                                         fx4 (&acc)[4][4], int q, int c){
  fx4 a2[4][2];
  #pragma unroll
  for (int nt = 0; nt < 2; ++nt){
    float bv = b2g[nt*16+c];
    fx4 v = {bv, bv, bv, bv};
    #pragma unroll
    for (int mt = 0; mt < 4; ++mt) a2[mt][nt] = v;
  }
  #pragma unroll
  for (int kt = 0; kt < 2; ++kt){
    int k = kt*32 + q*8;
    bfx8 f0 = ldfrag128(X,  0+c, k);
    bfx8 f1 = ldfrag128(X, 16+c, k);
    bfx8 f2 = ldfrag128(X, 32+c, k);
    bfx8 f3 = ldfrag128(X, 48+c, k);
    #pragma unroll
    for (int nt = 0; nt < 2; ++nt){
      a2[0][nt] = __builtin_amdgcn_mfma_f32_16x16x32_bf16(f0, u2[kt][nt], a2[0][nt], 0,0,0);
      a2[1][nt] = __builtin_amdgcn_mfma_f32_16x16x32_bf16(f1, u2[kt][nt], a2[1][nt], 0,0,0);
      a2[2][nt] = __builtin_amdgcn_mfma_f32_16x16x32_bf16(f2, u2[kt][nt], a2[2][nt], 0,0,0);
      a2[3][nt] = __builtin_amdgcn_mfma_f32_16x16x32_bf16(f3, u2[kt][nt], a2[3][nt], 0,0,0);
    }
  }
  #pragma unroll
  for (int mt = 0; mt < 4; ++mt)
    #pragma unroll
    for (int nt = 0; nt < 2; ++nt)
      #pragma unroll
      for (int i = 0; i < 4; ++i)
        stb16_64(X, mt*16+q*4+i, nt*16+c, fmaxf(a2[mt][nt][i], 0.f));
  // fc3
  #pragma unroll
  for (int nt = 0; nt < 4; ++nt){
    float bv = b3g[nt*16+c];
    fx4 v = {bv, bv, bv, bv};
    #pragma unroll
    for (int mt = 0; mt < 4; ++mt) acc[mt][nt] = v;
  }
  bfx8 g0 = ldfrag64(X,  0+c, q*8);
  bfx8 g1 = ldfrag64(X, 16+c, q*8);
  bfx8 g2 = ldfrag64(X, 32+c, q*8);
  bfx8 g3 = ldfrag64(X, 48+c, q*8);
  #pragma unroll
  for (int nt = 0; nt < 4; ++nt){
    acc[0][nt] = __builtin_amdgcn_mfma_f32_16x16x32_bf16(g0, u3[nt], acc[0][nt], 0,0,0);
    acc[1][nt] = __builtin_amdgcn_mfma_f32_16x16x32_bf16(g1, u3[nt], acc[1][nt], 0,0,0);
    acc[2][nt] = __builtin_amdgcn_mfma_f32_16x16x32_bf16(g2, u3[nt], acc[2][nt], 0,0,0);
    acc[3][nt] = __builtin_amdgcn_mfma_f32_16x16x32_bf16(g3, u3[nt], acc[3][nt], 0,0,0);
  }
}

// ---------- scalar helpers for the small kernels ----------
template<int CNT>
__device__ __forceinline__ void stage_w(float* dst, const float* __restrict__ src, int tid, int nth){
  for (int i = tid; i < CNT; i += nth) dst[i] = src[i];
}
__device__ __forceinline__ void stage_b(float* dst, const float* __restrict__ src, int n, int tid){
  if (tid < n) dst[tid] = src[tid];
}
template<int K, int N, int R, int XS>
__device__ __forceinline__ void layerR(const float* __restrict__ W,
                                       const float* __restrict__ x,
                                       float* __restrict__ acc, int j)
{
  #pragma unroll
  for (int k = 0; k < K; k += 4){
    float w0 = W[(k+0)*N + j];
    float w1 = W[(k+1)*N + j];
    float w2 = W[(k+2)*N + j];
    float w3 = W[(k+3)*N + j];
    #pragma unroll
    for (int r = 0; r < R; ++r){
      float4 xv = *(const float4*)(x + r*XS + k);
      acc[r] = fmaf(xv.x, w0, acc[r]);
      acc[r] = fmaf(xv.y, w1, acc[r]);
      acc[r] = fmaf(xv.z, w2, acc[r]);
      acc[r] = fmaf(xv.w, w3, acc[r]);
    }
  }
}
__device__ __forceinline__ int lbound(const int* __restrict__ a, int n, int v){
  int lo = 0, hi = n;
  while (lo < hi){ int m = (lo+hi) >> 1; if (a[m] < v) lo = m+1; else hi = m; }
  return lo;
}

// ---------- kernel 1: states path prep (1000 rows, scalar, validated) ----------
__global__ __launch_bounds__(256) void prep_small_kernel(
    const float* __restrict__ states,
    const float* __restrict__ w1, const float* __restrict__ b1,
    const float* __restrict__ w2, const float* __restrict__ b2,
    const float* __restrict__ w_bu1, const float* __restrict__ b_bu1,
    const float* __restrict__ w_su1, const float* __restrict__ b_su1,
    const float* __restrict__ w_stu1, const float* __restrict__ b_stu1,
    float* __restrict__ states2, float* __restrict__ statec_bu,
    float* __restrict__ statec_su, float* __restrict__ statec_stu)
{
  __shared__ float W1[4096], W2[4096], WD[4096], WsuC[4096], WstuC[4096];
  __shared__ float B1[64], B2[64], Bbu[64], Bsu[64], Bstu[64];
  __shared__ alignas(16) float xs[4][64];
  __shared__ alignas(16) float hs[4][64];
  int tid = threadIdx.x;
  stage_w<4096>(W1,    w1,              tid, 256);
  stage_w<4096>(W2,    w2,              tid, 256);
  stage_w<4096>(WD,    w_bu1 + 192*64,  tid, 256);
  stage_w<4096>(WsuC,  w_su1 + 128*64,  tid, 256);
  stage_w<4096>(WstuC, w_stu1 + 128*64, tid, 256);
  stage_b(B1, b1, 64, tid);  stage_b(B2, b2, 64, tid);
  stage_b(Bbu, b_bu1, 64, tid); stage_b(Bsu, b_su1, 64, tid); stage_b(Bstu, b_stu1, 64, tid);
  __syncthreads();
  int w = tid >> 6, lane = tid & 63;
  int g = blockIdx.x*4 + w;
  xs[w][lane] = states[(size_t)g*64 + lane];
  float a = B1[lane];
  layerR<64,64,1,64>(W1, xs[w], &a, lane);
  hs[w][lane] = fmaxf(a, 0.f);
  a = B2[lane];
  layerR<64,64,1,64>(W2, hs[w], &a, lane);
  float s2 = fmaxf(a, 0.f);
  xs[w][lane] = s2;
  size_t o = (size_t)g*64 + lane;
  float abu = Bbu[lane], asu = Bsu[lane], astu = Bstu[lane];
  layerR<64,64,1,64>(WD,    xs[w], &abu,  lane);
  layerR<64,64,1,64>(WsuC,  xs[w], &asu,  lane);
  layerR<64,64,1,64>(WstuC, xs[w], &astu, lane);
  states2[o]    = s2;
  statec_bu[o]  = abu;
  statec_su[o]  = asu;
  statec_stu[o] = astu;
}

// ---------- kernel 2: sites pre-MLP (MFMA, 64 rows/wave) ----------
// LDS 48 KB -> 3 blocks/CU = 12 waves/CU.
__global__ __launch_bounds__(256) void sites_pre_kernel(
    const float* __restrict__ sites,
    const float* __restrict__ w1, const float* __restrict__ b1,
    const float* __restrict__ w2, const float* __restrict__ b2,
    float* __restrict__ sites2)
{
  __shared__ alignas(16) short WT1[4096], WT2[4096];
  __shared__ alignas(16) short Xb[4][4096];
  int tid = threadIdx.x;
  stage_wt(WT1, w1, tid, 256);
  stage_wt(WT2, w2, tid, 256);
  __syncthreads();
  int w = tid >> 6, lane = tid & 63, q = lane >> 4, c = lane & 15;
  int c0 = (blockIdx.x*4 + w) * 64;          // 391*4 = 1564 chunks >= 1563
  if (c0 >= N_SITES) return;
  short* X = Xb[w];
  fx4 acc[4][4];
  initbiasG(acc, b1, c);
  {
    const float* rp[4];
    #pragma unroll
    for (int mt = 0; mt < 4; ++mt){
      int r = c0 + mt*16 + c; if (r > N_SITES-1) r = N_SITES-1;
      rp[mt] = sites + (size_t)r*64;
    }
    gemmG(rp, WT1, acc, q, c);
  }
  wbC128(X, acc, q, c);
  initbiasG(acc, b2, c);
  gemm64(X, WT2, acc, q, c);
  #pragma unroll
  for (int mt = 0; mt < 4; ++mt)
    #pragma unroll
    for (int nt = 0; nt < 4; ++nt)
      #pragma unroll
      for (int i = 0; i < 4; ++i){
        int row = c0 + mt*16 + q*4 + i;
        if (row < N_SITES)
          sites2[(size_t)row*64 + nt*16 + c] = fmaxf(acc[mt][nt][i], 0.f);
      }
}

// ---------- kernel 3: MFMA bond kernel v2 ----------
// vs round 6 (500us, 1 wave/SIMD, 77% idle): direct-global A-frags for
// bonds/S1/S2 (no gather staging), single per-wave X (H->B2->H1->H2 in
// place), B2 residual written f32 to out_bonds at L2 and RMW'd at the
// epilogue (rows wave-exclusive), WU2/WU3 as register B-frags.
// LDS = 40KB weights + 32KB X = 73.7KB -> 2 blocks/CU = 8 waves/CU.
__global__ __launch_bounds__(256) void bond_kernel(
    const float* __restrict__ bonds,
    const float* __restrict__ wb1, const float* __restrict__ bb1,
    const float* __restrict__ wb2, const float* __restrict__ bb2,
    const float* __restrict__ w_bu1,
    const float* __restrict__ w_bu2, const float* __restrict__ b_bu2,
    const float* __restrict__ w_bu3, const float* __restrict__ b_bu3,
    const int* __restrict__ idx1, const int* __restrict__ idx2, const int* __restrict__ g2b,
    const float* __restrict__ sites2, const float* __restrict__ statec_bu,
    float* __restrict__ bonds_pool, int* __restrict__ cnt_pool, float* __restrict__ bonds_g,
    float* __restrict__ out_bonds)
{
  __shared__ alignas(16) short WT1[4096], WT2[4096], WTA[4096], WTB[4096], WTC[4096];
  __shared__ alignas(16) short Xb[4][4096];
  int tid = threadIdx.x;
  stage_wt(WT1, wb1,            tid, 256);
  stage_wt(WT2, wb2,            tid, 256);
  stage_wt(WTA, w_bu1,          tid, 256);
  stage_wt(WTB, w_bu1 + 64*64,  tid, 256);
  stage_wt(WTC, w_bu1 + 128*64, tid, 256);
  __syncthreads();
  int w = tid >> 6, lane = tid & 63, q = lane >> 4, c = lane & 15;
  int e0 = (blockIdx.x*4 + w) * 64;          // 3125*4*64 = exactly 800000
  short* X = Xb[w];

  bfx8 u2[2][2], u3[4];
  preload_tail(w_bu2, w_bu3, u2, u3, q, c);

  atomicAdd(&cnt_pool[idx1[e0 + lane]], 1);

  int gr[4][4];                               // graph ids for this lane's C/D rows
  #pragma unroll
  for (int mt = 0; mt < 4; ++mt)
    #pragma unroll
    for (int i = 0; i < 4; ++i)
      gr[mt][i] = g2b[e0 + mt*16 + q*4 + i];

  fx4 acc[4][4];
  // L1: H = relu(bonds @ W1 + b1) -> X
  initbiasG(acc, bb1, c);
  {
    const float* rp[4];
    #pragma unroll
    for (int mt = 0; mt < 4; ++mt) rp[mt] = bonds + (size_t)(e0 + mt*16 + c)*64;
    gemmG(rp, WT1, acc, q, c);
  }
  wbC128(X, acc, q, c);
  // L2: B2 = relu(H @ W2 + b2); f32 to out_bonds, bf16 to X (in place)
  initbiasG(acc, bb2, c);
  gemm64(X, WT2, acc, q, c);
  #pragma unroll
  for (int mt = 0; mt < 4; ++mt)
    #pragma unroll
    for (int nt = 0; nt < 4; ++nt)
      #pragma unroll
      for (int i = 0; i < 4; ++i){
        float b2v = fmaxf(acc[mt][nt][i], 0.f);
        int row = mt*16 + q*4 + i, col = nt*16 + c;
        out_bonds[(size_t)(e0 + row)*64 + col] = b2v;
        stb16_128(X, row, col, b2v);
      }
  // fc1: statec_bu (incl. b_bu1) + S1@WA + S2@WB + B2@WC -> H1 -> X
  #pragma unroll
  for (int mt = 0; mt < 4; ++mt)
    #pragma unroll
    for (int i = 0; i < 4; ++i)
      #pragma unroll
      for (int nt = 0; nt < 4; ++nt)
        acc[mt][nt][i] = statec_bu[(size_t)gr[mt][i]*64 + nt*16 + c];
  {
    const float* rp[4];
    #pragma unroll
    for (int mt = 0; mt < 4; ++mt) rp[mt] = sites2 + (size_t)idx1[e0 + mt*16 + c]*64;
    gemmG(rp, WTA, acc, q, c);
  }
  {
    const float* rp[4];
    #pragma unroll
    for (int mt = 0; mt < 4; ++mt) rp[mt] = sites2 + (size_t)idx2[e0 + mt*16 + c]*64;
    gemmG(rp, WTB, acc, q, c);
  }
  gemm64(X, WTC, acc, q, c);
  wbC128(X, acc, q, c);                       // H1 (B2 consumed; residual in out_bonds)
  // fc2 + fc3
  tail3264(X, u2, u3, b_bu2, b_bu3, acc, q, c);
  // epilogue
  int i1r[4][4];
  #pragma unroll
  for (int mt = 0; mt < 4; ++mt)
    #pragma unroll
    for (int i = 0; i < 4; ++i)
      i1r[mt][i] = idx1[e0 + mt*16 + q*4 + i];
  #pragma unroll
  for (int nt = 0; nt < 4; ++nt){
    int col = nt*16 + c;
    float ga = 0.f; int cg = -1;
    #pragma unroll
    for (int mt = 0; mt < 4; ++mt)
      #pragma unroll
      for (int i = 0; i < 4; ++i){
        int row = mt*16 + q*4 + i;
        float bn = fmaxf(acc[mt][nt][i], 0.f);
        size_t o = (size_t)(e0 + row)*64 + col;
        out_bonds[o] = bn + out_bonds[o];     // + B2 residual (written at L2)
        atomicAdd(&bonds_pool[(size_t)i1r[mt][i]*64 + col], bn);
        int g = gr[mt][i];
        if (g != cg){
          if (cg >= 0) atomicAdd(&bonds_g[(size_t)cg*64 + col], ga);
          cg = g; ga = 0.f;
        }
        ga += bn;
      }
    if (cg >= 0) atomicAdd(&bonds_g[(size_t)cg*64 + col], ga);
  }
}

// ---------- kernel 4: MFMA site kernel (64 sites/wave) ----------
// LDS 48 KB -> 3 blocks/CU. In-place out_sites RMW: all sites2 reads are
// data-deps of gemms preceding the epilogue stores in lockstep order, and
// each (row,col) is touched by exactly one iteration of one wave.
__global__ __launch_bounds__(256) void site_kernel(
    const float* __restrict__ sites2, const float* __restrict__ bonds_pool, const int* __restrict__ cnt_pool,
    const int* __restrict__ g2s, const float* __restrict__ statec_su,
    const float* __restrict__ w_su1, const float* __restrict__ w_su2, const float* __restrict__ b_su2,
    const float* __restrict__ w_su3, const float* __restrict__ b_su3,
    float* __restrict__ sites_g, float* __restrict__ out_sites)
{
  __shared__ alignas(16) short WTa[4096], WTb[4096];
  __shared__ alignas(16) short Xb[4][4096];
  int tid = threadIdx.x;
  stage_wt(WTa, w_su1,         tid, 256);
  stage_wt(WTb, w_su1 + 64*64, tid, 256);
  __syncthreads();
  int w = tid >> 6, lane = tid & 63, q = lane >> 4, c = lane & 15;
  int s0 = (blockIdx.x*4 + w) * 64;           // 391*4 = 1564 chunks >= 1563
  if (s0 >= N_SITES) return;
  short* X = Xb[w];

  bfx8 u2[2][2], u3[4];
  preload_tail(w_su2, w_su3, u2, u3, q, c);

  int gr[4][4];
  #pragma unroll
  for (int mt = 0; mt < 4; ++mt)
    #pragma unroll
    for (int i = 0; i < 4; ++i){
      int r = s0 + mt*16 + q*4 + i; if (r > N_SITES-1) r = N_SITES-1;
      gr[mt][i] = g2s[r];
    }
  fx4 acc[4][4];
  #pragma unroll
  for (int mt = 0; mt < 4; ++mt)
    #pragma unroll
    for (int i = 0; i < 4; ++i)
      #pragma unroll
      for (int nt = 0; nt < 4; ++nt)
        acc[mt][nt][i] = statec_su[(size_t)gr[mt][i]*64 + nt*16 + c];
  {
    const float* rp[4]; float sc[4];
    #pragma unroll
    for (int mt = 0; mt < 4; ++mt){
      int r = s0 + mt*16 + c; if (r > N_SITES-1) r = N_SITES-1;
      rp[mt] = bonds_pool + (size_t)r*64;
      sc[mt] = 1.f / fmaxf((float)cnt_pool[r], 1.f);
    }
    gemmGs(rp, sc, WTa, acc, q, c);
  }
  {
    const float* rp[4];
    #pragma unroll
    for (int mt = 0; mt < 4; ++mt){
      int r = s0 + mt*16 + c; if (r > N_SITES-1) r = N_SITES-1;
      rp[mt] = sites2 + (size_t)r*64;
    }
    gemmG(rp, WTb, acc, q, c);
  }
  wbC128(X, acc, q, c);                       // H1
  tail3264(X, u2, u3, b_su2, b_su3, acc, q, c);
  #pragma unroll
  for (int nt = 0; nt < 4; ++nt){
    int col = nt*16 + c;
    float ga = 0.f; int cg = -1;
    #pragma unroll
    for (int mt = 0; mt < 4; ++mt)
      #pragma unroll
      for (int i = 0; i < 4; ++i){
        int s = s0 + mt*16 + q*4 + i;
        if (s < N_SITES){
          float sn = fmaxf(acc[mt][nt][i], 0.f);
          size_t o = (size_t)s*64 + col;
          float s2 = sites2[o];               // same buffer as out_sites (in-place)
          out_sites[o] = sn + s2;
          int g = gr[mt][i];
          if (g != cg){
            if (cg >= 0) atomicAdd(&sites_g[(size_t)cg*64 + col], ga);
            cg = g; ga = 0.f;
          }
          ga += sn;
        }
      }
    if (cg >= 0) atomicAdd(&sites_g[(size_t)cg*64 + col], ga);
  }
}

// ---------- kernel 5: state update (1000 graphs, scalar, validated) ----------
__global__ __launch_bounds__(64) void state_kernel(
    const float* __restrict__ states2, const float* __restrict__ bonds_g, const float* __restrict__ sites_g,
    const int* __restrict__ g2b, const int* __restrict__ g2s,
    const float* __restrict__ w_stu1, const float* __restrict__ w_stu2, const float* __restrict__ b_stu2,
    const float* __restrict__ w_stu3, const float* __restrict__ b_stu3,
    const float* __restrict__ statec_stu, float* __restrict__ out_states)
{
  __shared__ float W1a[4096], W1b[4096], W2[2048], W3[2048];
  __shared__ float B2s[32], B3s[64];
  __shared__ alignas(16) float xb[64], xsit[64], hsx[64], h2x[32];
  __shared__ int cnts[2];
  int lane = threadIdx.x; int g = blockIdx.x;
  stage_w<4096>(W1a, w_stu1,         lane, 64);
  stage_w<4096>(W1b, w_stu1 + 64*64, lane, 64);
  stage_w<2048>(W2,  w_stu2,         lane, 64);
  stage_w<2048>(W3,  w_stu3,         lane, 64);
  stage_b(B2s, b_stu2, 32, lane); stage_b(B3s, b_stu3, 64, lane);
  if (lane == 0){
    cnts[0] = lbound(g2b, N_BONDS, g+1) - lbound(g2b, N_BONDS, g);
    cnts[1] = lbound(g2s, N_SITES, g+1) - lbound(g2s, N_SITES, g);
  }
  __syncthreads();
  float invb = 1.f / fmaxf((float)cnts[0], 1.f);
  float invs = 1.f / fmaxf((float)cnts[1], 1.f);
  xb[lane]   = bonds_g[(size_t)g*64 + lane] * invb;
  xsit[lane] = sites_g[(size_t)g*64 + lane] * invs;
  __syncthreads();
  {
    float a = statec_stu[(size_t)g*64 + lane];
    layerR<64,64,1,64>(W1a, xb,   &a, lane);
    layerR<64,64,1,64>(W1b, xsit, &a, lane);
    hsx[lane] = fmaxf(a, 0.f);
  }
  __syncthreads();
  {
    int j = lane & 31;
    float a = B2s[j];
    layerR<64,32,1,64>(W2, hsx, &a, j);
    if (lane < 32) h2x[lane] = fmaxf(a, 0.f);
  }
  __syncthreads();
  {
    float a = B3s[lane];
    layerR<32,64,1,32>(W3, h2x, &a, lane);
    out_states[(size_t)g*64 + lane] = fmaxf(a, 0.f) + states2[(size_t)g*64 + lane];
  }
}

// ---------- launch ----------
extern "C" void kernel_launch(void* const* d_in, const int* in_sizes, int n_in,
                              void* d_out, int out_size, void* d_ws, size_t ws_size,
                              hipStream_t stream)
{
  const float* sites   = (const float*)d_in[0];
  const float* bonds   = (const float*)d_in[1];
  const float* states  = (const float*)d_in[2];
  const float* w_sites1 = (const float*)d_in[3];  const float* b_sites1 = (const float*)d_in[4];
  const float* w_sites2 = (const float*)d_in[5];  const float* b_sites2 = (const float*)d_in[6];
  const float* w_bonds1 = (const float*)d_in[7];  const float* b_bonds1 = (const float*)d_in[8];
  const float* w_bonds2 = (const float*)d_in[9];  const float* b_bonds2 = (const float*)d_in[10];
  const float* w_states1= (const float*)d_in[11]; const float* b_states1= (const float*)d_in[12];
  const float* w_states2= (const float*)d_in[13]; const float* b_states2= (const float*)d_in[14];
  const float* w_bu1 = (const float*)d_in[15]; const float* b_bu1 = (const float*)d_in[16];
  const float* w_bu2 = (const float*)d_in[17]; const float* b_bu2 = (const float*)d_in[18];
  const float* w_bu3 = (const float*)d_in[19]; const float* b_bu3 = (const float*)d_in[20];
  const float* w_su1 = (const float*)d_in[21]; const float* b_su1 = (const float*)d_in[22];
  const float* w_su2 = (const float*)d_in[23]; const float* b_su2 = (const float*)d_in[24];
  const float* w_su3 = (const float*)d_in[25]; const float* b_su3 = (const float*)d_in[26];
  const float* w_stu1= (const float*)d_in[27]; const float* b_stu1= (const float*)d_in[28];
  const float* w_stu2= (const float*)d_in[29]; const float* b_stu2= (const float*)d_in[30];
  const float* w_stu3= (const float*)d_in[31]; const float* b_stu3= (const float*)d_in[32];
  const int* idx1 = (const int*)d_in[33];
  const int* idx2 = (const int*)d_in[34];
  const int* g2s  = (const int*)d_in[35];
  const int* g2b  = (const int*)d_in[36];

  // d_ws usage: ~27.6 MB
  float* p = (float*)d_ws;
  float* bonds_pool = p;        p += (size_t)N_SITES*64;     // zeroed
  float* bonds_g    = p;        p += (size_t)N_GRAPHS*64;    // zeroed
  float* sites_g    = p;        p += (size_t)N_GRAPHS*64;    // zeroed
  int*   cnt_pool   = (int*)p;  p += N_SITES;                // zeroed
  float* states2    = p;        p += (size_t)N_GRAPHS*64;
  float* statec_bu  = p;        p += (size_t)N_GRAPHS*64;
  float* statec_su  = p;        p += (size_t)N_GRAPHS*64;
  float* statec_stu = p;        p += (size_t)N_GRAPHS*64;

  size_t zero_bytes = ((size_t)N_SITES*64 + 2*(size_t)N_GRAPHS*64 + (size_t)N_SITES) * 4;
  hipMemsetAsync(d_ws, 0, zero_bytes, stream);

  float* out_sites  = (float*)d_out;
  float* out_bonds  = out_sites + (size_t)N_SITES*64;
  float* out_states = out_bonds + (size_t)N_BONDS*64;
  float* sites2     = out_sites;   // fp32 sites2 staged in the sites output region

  hipLaunchKernelGGL(prep_small_kernel, dim3(250), dim3(256), 0, stream,
      states, w_states1, b_states1, w_states2, b_states2,
      w_bu1, b_bu1, w_su1, b_su1, w_stu1, b_stu1,
      states2, statec_bu, statec_su, statec_stu);

  // 1563 chunks of 64 sites, 4 waves/block -> 391 blocks
  hipLaunchKernelGGL(sites_pre_kernel, dim3(391), dim3(256), 0, stream,
      sites, w_sites1, b_sites1, w_sites2, b_sites2, sites2);

  // 12500 wave-chunks of 64 bonds, 4 waves/block -> 3125 blocks (exact)
  hipLaunchKernelGGL(bond_kernel, dim3(3125), dim3(256), 0, stream,
      bonds, w_bonds1, b_bonds1, w_bonds2, b_bonds2,
      w_bu1, w_bu2, b_bu2, w_bu3, b_bu3,
      idx1, idx2, g2b, sites2, statec_bu,
      bonds_pool, cnt_pool, bonds_g, out_bonds);

  hipLaunchKernelGGL(site_kernel, dim3(391), dim3(256), 0, stream,
      sites2, bonds_pool, cnt_pool, g2s, statec_su,
      w_su1, w_su2, b_su2, w_su3, b_su3,
      sites_g, out_sites);

  hipLaunchKernelGGL(state_kernel, dim3(1000), dim3(64), 0, stream,
      states2, bonds_g, sites_g, g2b, g2s,
      w_stu1, w_stu2, b_stu2, w_stu3, b_stu3,
      statec_stu, out_states);
}